// Round 7
// baseline (191.586 us; speedup 1.0000x reference)
//
#include <hip/hip_runtime.h>
#include <hip/hip_bf16.h>
#include <math.h>

#define BB 16
#define CC 256
#define HWP 9216
#define DD 64
#define MM 64

typedef __attribute__((ext_vector_type(8))) short bf16x8;
typedef __attribute__((ext_vector_type(4))) short s16x4;
typedef __attribute__((ext_vector_type(4))) float f32x4;

__device__ inline unsigned short f2bf(float f) {
    __hip_bfloat16 h = __float2bfloat16(f);
    return *reinterpret_cast<unsigned short*>(&h);
}
__device__ inline float bf2f(unsigned short h) {
    return __uint_as_float(((unsigned)h) << 16);
}

// workspace layout (bytes)
#define WS_SCORES_B 0u                    // fp32 16*9216*4        = 589824
#define WS_PROJ_B   589824u               // bf16 packed 16*589824 halfs = 18874368 B
#define WS_HG_B     19464192u             // fp32 16*64*64*4       = 262144
#define WS_HGPK_B   19726336u             // bf16 16*4096*2        = 131072
#define WS_GPK_B    19857408u             // bf16 16*16384*2       = 524288
#define WS_WPK_B    20381696u             // bf16 packed W, 65536
#define WS_FMAPH_B  20447232u             // bf16 fmap copy 16*256*9216*2 = 75497472
// total ~95.9 MB

#define PPB 589824u   // projPk halfs per batch: 144*4*2*64*8

// k index bijection used by ALL fragments (HW-verified rounds 2-6):
// kmap(g, j) = j<4 ? g*4+j : 16+g*4+(j-4)
// A-frag: lane l holds A[row = l&15][k = kmap(l>>4, j)]
// B-frag: lane l holds B[col = l&15][k = kmap(l>>4, j)]
// D: lane l holds D[row = (l>>4)*4 + r][col = l&15]

// ---------------------------------------------------------------------------
// Prep: pack W = [ws1 (64,256); wt2n (64,256)] into per-lane MFMA A-fragment
// order. Layout: wpk[((obg*8 + ks)*64 + lane)*8 + j]. grid 128 x 256.
// ---------------------------------------------------------------------------
__global__ __launch_bounds__(256) void k_prep(
    const float* __restrict__ ws1, const float* __restrict__ wt2n,
    unsigned short* __restrict__ wpk)
{
    const int tid = blockIdx.x * 256 + threadIdx.x;     // 0..32767
    const int i  = tid & 7;
    const int l  = (tid >> 3) & 63;
    const int ks = (tid >> 9) & 7;
    const int ob = tid >> 12;                           // obg 0..7
    const int o = ob * 16 + (l & 15);
    const int g = l >> 4;
    const int k = ks * 32 + (i < 4 ? 4 * g + i : 16 + 4 * g + (i - 4));
    const float v = (o < 64) ? ws1[o * CC + k] : wt2n[(o - 64) * CC + k];
    wpk[tid] = f2bf(v);
}

// ---------------------------------------------------------------------------
// Kernel A (MFMA): D[128][64] = W * F per 64-position tile.
// Also emits fmapH = bf16(fmap) in [c][p] layout for k_inject's residual
// (kills inject's 151 MB fp32 re-read; costs a 75 MB bf16 write).
// LDS layout permuted so each B-fragment is one aligned ds_read_b128.
// grid (144, B), block 256 (4 waves). Wave w computes obg {2w, 2w+1}.
// ---------------------------------------------------------------------------
#define LP 272   // LDS row pitch in halfs (544 B)

__global__ __launch_bounds__(256) void k_mfma_a(
    const float* __restrict__ fmap, const unsigned short* __restrict__ wpk,
    const float* __restrict__ bs1, const float* __restrict__ ws2,
    const float* __restrict__ bs2,
    float* __restrict__ scores, unsigned short* __restrict__ projPk,
    unsigned short* __restrict__ fmapH)
{
    __shared__ unsigned short fL[64 * LP];   // 34816 B
    __shared__ float scoreP[8 * 64];

    const int b = blockIdx.y;
    const int tile = blockIdx.x;
    const int p0 = tile * 64;
    const int t = threadIdx.x;
    const int w = t >> 6, l = t & 63;
    const int g = l >> 4, c16 = l & 15;

    // A-frag prefetch: wave w owns obg {2w, 2w+1}; 16 x dwordx4 from L2
    const bf16x8* wp = (const bf16x8*)wpk;
    bf16x8 afr[2][8];
#pragma unroll
    for (int ob = 0; ob < 2; ++ob) {
        const int obg = w * 2 + ob;
#pragma unroll
        for (int ks = 0; ks < 8; ++ks) afr[ob][ks] = wp[(obg * 8 + ks) * 64 + l];
    }

    // stage fmap tile -> LDS bf16 (permuted) + bf16 copy to fmapH
    const float* fb = fmap + (size_t)b * CC * HWP + p0;
    unsigned short* fH = fmapH + (size_t)b * CC * HWP + p0;
    const int n0 = (t & 15) * 4;
    const int cbase = (t >> 4) * 4;          // 0..60
#pragma unroll
    for (int iter = 0; iter < 4; ++iter) {
        const int c0 = iter * 64 + cbase;
        const int within = c0 & 31;
        const int pp = (c0 >> 5) * 32 + ((within >> 2) & 3) * 8 + (within >> 4) * 4;
        float4 v0 = *(const float4*)&fb[(size_t)(c0 + 0) * HWP + n0];
        float4 v1 = *(const float4*)&fb[(size_t)(c0 + 1) * HWP + n0];
        float4 v2 = *(const float4*)&fb[(size_t)(c0 + 2) * HWP + n0];
        float4 v3 = *(const float4*)&fb[(size_t)(c0 + 3) * HWP + n0];

        // bf16 copy (coalesced 8B rows over n)
        s16x4 h;
        h[0] = (short)f2bf(v0.x); h[1] = (short)f2bf(v0.y);
        h[2] = (short)f2bf(v0.z); h[3] = (short)f2bf(v0.w);
        *(s16x4*)&fH[(size_t)(c0 + 0) * HWP + n0] = h;
        h[0] = (short)f2bf(v1.x); h[1] = (short)f2bf(v1.y);
        h[2] = (short)f2bf(v1.z); h[3] = (short)f2bf(v1.w);
        *(s16x4*)&fH[(size_t)(c0 + 1) * HWP + n0] = h;
        h[0] = (short)f2bf(v2.x); h[1] = (short)f2bf(v2.y);
        h[2] = (short)f2bf(v2.z); h[3] = (short)f2bf(v2.w);
        *(s16x4*)&fH[(size_t)(c0 + 2) * HWP + n0] = h;
        h[0] = (short)f2bf(v3.x); h[1] = (short)f2bf(v3.y);
        h[2] = (short)f2bf(v3.z); h[3] = (short)f2bf(v3.w);
        *(s16x4*)&fH[(size_t)(c0 + 3) * HWP + n0] = h;

        // LDS transpose writes (permuted channel order, bank-swizzled)
#pragma unroll
        for (int i = 0; i < 4; ++i) {
            const int n = n0 + i;
            const float a0 = (i == 0) ? v0.x : (i == 1) ? v0.y : (i == 2) ? v0.z : v0.w;
            const float a1 = (i == 0) ? v1.x : (i == 1) ? v1.y : (i == 2) ? v1.z : v1.w;
            const float a2 = (i == 0) ? v2.x : (i == 1) ? v2.y : (i == 2) ? v2.z : v2.w;
            const float a3 = (i == 0) ? v3.x : (i == 1) ? v3.y : (i == 2) ? v3.z : v3.w;
            s16x4 o;
            o[0] = (short)f2bf(a0); o[1] = (short)f2bf(a1);
            o[2] = (short)f2bf(a2); o[3] = (short)f2bf(a3);
            const unsigned byteoff = (unsigned)((n * LP + pp) * 2) ^ ((n & 7) << 4);
            *(s16x4*)((char*)fL + byteoff) = o;
        }
    }
    __syncthreads();

    f32x4 acc[2][4] = {};

#pragma unroll
    for (int ks = 0; ks < 8; ++ks) {
        bf16x8 bfr[4];
#pragma unroll
        for (int nb = 0; nb < 4; ++nb) {
            const int n = nb * 16 + c16;
            const unsigned byteoff =
                (unsigned)((n * LP + ks * 32 + g * 8) * 2) ^ ((n & 7) << 4);
            bfr[nb] = *(const bf16x8*)((const char*)fL + byteoff);
        }
#pragma unroll
        for (int ob = 0; ob < 2; ++ob)
#pragma unroll
            for (int nb = 0; nb < 4; ++nb)
                acc[ob][nb] = __builtin_amdgcn_mfma_f32_16x16x32_bf16(
                    afr[ob][ks], bfr[nb], acc[ob][nb], 0, 0, 0);
    }

    // epilogue. D element: row o_loc = g*4 + r, col n_loc = c16 (per nb).
    if (w < 2) {
        float sp[4] = {0.f, 0.f, 0.f, 0.f};
#pragma unroll
        for (int ob = 0; ob < 2; ++ob) {
            const int obase = w * 32 + ob * 16 + g * 4;
#pragma unroll
            for (int r = 0; r < 4; ++r) {
                const int o = obase + r;
                const float b1 = bs1[o], w2 = ws2[o];
#pragma unroll
                for (int nb = 0; nb < 4; ++nb) {
                    const float h = acc[ob][nb][r] + b1;
                    sp[nb] += w2 * fmaxf(h, 0.f);
                }
            }
        }
        const int gw = w * 4 + g;
#pragma unroll
        for (int nb = 0; nb < 4; ++nb) scoreP[gw * 64 + nb * 16 + c16] = sp[nb];
    } else {
        // proj rows: wave 2 -> obg {4,5} (ks=0), wave 3 -> obg {6,7} (ks=1)
        const int ks = w - 2;
        unsigned short* pb = projPk + (size_t)b * PPB;
#pragma unroll
        for (int nb = 0; nb < 4; ++nb) {
            bf16x8 pk;
#pragma unroll
            for (int r = 0; r < 4; ++r) {
                pk[r]     = (short)f2bf(acc[0][nb][r]);
                pk[4 + r] = (short)f2bf(acc[1][nb][r]);
            }
            *(bf16x8*)&pb[(size_t)(((tile * 4 + nb) * 2 + ks) * 64 + l) * 8] = pk;
        }
    }
    __syncthreads();
    if (t < 64) {
        float s = bs2[0];
#pragma unroll
        for (int gw = 0; gw < 8; ++gw) s += scoreP[gw * 64 + t];
        scores[b * HWP + p0 + t] = s;
    }
}

// ---------------------------------------------------------------------------
// Kernel B: radix-select top-64 (4 per-wave sub-histograms) + cosine
// adjacency + 2-layer GCN. grid (B), block 256.
// ---------------------------------------------------------------------------
__global__ __launch_bounds__(256) void k_graph(
    const float* __restrict__ scores, const unsigned short* __restrict__ projPk,
    const float* __restrict__ wg1, const float* __restrict__ wg2,
    float* __restrict__ HgOut, unsigned short* __restrict__ HgPk)
{
    __shared__ float h0x[64 * 65];
    __shared__ float bufA[64 * 65];
    __shared__ float bufT[64 * 65];
    __shared__ int hist4[1024];          // 4 sub-histograms (one per wave)
    __shared__ int idxL[64];
    __shared__ int eqIdx[64];
    __shared__ int sInts[8];
    __shared__ float norms[64], rsum[64];

    const int b = blockIdx.x;
    const int t = threadIdx.x;
    const int wv = t >> 6;

    unsigned uv[36];
#pragma unroll
    for (int i = 0; i < 36; ++i) {
        const unsigned u = __float_as_uint(scores[b * HWP + i * 256 + t]);
        uv[i] = (u >> 31) ? ~u : (u | 0x80000000u);
    }

    unsigned prefix = 0;
    int need = 64;
    for (int pass = 0; pass < 4; ++pass) {
        const int shift = 24 - 8 * pass;
#pragma unroll
        for (int i = 0; i < 4; ++i) hist4[t + 256 * i] = 0;
        __syncthreads();
#pragma unroll
        for (int i = 0; i < 36; ++i) {
            const bool ok = (pass == 0) || ((uv[i] >> (shift + 8)) == prefix);
            if (ok) atomicAdd(&hist4[(wv << 8) + ((uv[i] >> shift) & 255)], 1);
        }
        __syncthreads();
        if (t < 64) {
            const int l = t;
            int h0 = 0, h1 = 0, h2 = 0, h3 = 0;
#pragma unroll
            for (int i = 0; i < 4; ++i) {
                h0 += hist4[i * 256 + 4 * l + 0];
                h1 += hist4[i * 256 + 4 * l + 1];
                h2 += hist4[i * 256 + 4 * l + 2];
                h3 += hist4[i * 256 + 4 * l + 3];
            }
            const int T = h0 + h1 + h2 + h3;
            int S = T;
            for (int st = 1; st < 64; st <<= 1) {
                const int v = __shfl_down(S, st, 64);
                if (l + st < 64) S += v;
            }
            const int Sexc = S - T;
            const int ge3 = Sexc + h3, ge2 = ge3 + h2, ge1 = ge2 + h1, ge0 = ge1 + h0;
            if (ge3 - h3 < need && need <= ge3) { sInts[0] = 4 * l + 3; sInts[1] = ge3 - h3; }
            if (ge2 - h2 < need && need <= ge2) { sInts[0] = 4 * l + 2; sInts[1] = ge2 - h2; }
            if (ge1 - h1 < need && need <= ge1) { sInts[0] = 4 * l + 1; sInts[1] = ge1 - h1; }
            if (ge0 - h0 < need && need <= ge0) { sInts[0] = 4 * l + 0; sInts[1] = ge0 - h0; }
        }
        __syncthreads();
        prefix = (prefix << 8) | (unsigned)sInts[0];
        need -= sInts[1];
        __syncthreads();
    }

    if (t == 0) { sInts[2] = 0; sInts[3] = 0; }
    __syncthreads();
    const unsigned P = prefix;
    const int needEq = need;
#pragma unroll
    for (int i = 0; i < 36; ++i) {
        const unsigned u = uv[i];
        const int idx = i * 256 + t;
        if (u > P) { const int p = atomicAdd(&sInts[2], 1); idxL[p] = idx; }
        else if (u == P) { const int p = atomicAdd(&sInts[3], 1); if (p < 64) eqIdx[p] = idx; }
    }
    __syncthreads();
    if (t == 0) {
        int ec = sInts[3]; if (ec > 64) ec = 64;
        const int base = sInts[2];
        for (int k2 = 0; k2 < needEq; ++k2) {
            int mn = 0x7FFFFFFF, mi = 0;
            for (int j = 0; j < ec; ++j) if (eqIdx[j] < mn) { mn = eqIdx[j]; mi = j; }
            idxL[base + k2] = mn; eqIdx[mi] = 0x7FFFFFFF;
        }
    }
    __syncthreads();

    // gather H0[m][d] from fragment-packed proj
    const unsigned short* pb = projPk + (size_t)b * PPB;
    for (int e = t; e < 4096; e += 256) {
        const int m = e >> 6, d = e & 63;
        const int idx = idxL[m];
        const int tile = idx >> 6, nl = idx & 63;
        const int nb = nl >> 4, c16 = nl & 15;
        const int ks = d >> 5, dm = d & 31;
        const int gg = (dm & 15) >> 2;
        const int j = (dm & 3) + ((dm >= 16) ? 4 : 0);
        h0x[m * 65 + d] = bf2f(pb[(size_t)((((tile * 4 + nb) * 2 + ks) * 64 + gg * 16 + c16) * 8 + j)]);
    }
    __syncthreads();

    if (t < 64) {
        float s = 0.f;
        for (int d = 0; d < 64; ++d) { const float v = h0x[t * 65 + d]; s = fmaf(v, v, s); }
        norms[t] = fmaxf(sqrtf(s), 1e-6f);
    }
    __syncthreads();

    for (int e = t; e < 4096; e += 256) {
        const int m = e >> 6, nn = e & 63;
        float a = 0.f;
        for (int d = 0; d < 64; ++d) a = fmaf(h0x[m * 65 + d], h0x[nn * 65 + d], a);
        a = fmaxf(a / (norms[m] * norms[nn]), 0.f) + (m == nn ? 1.f : 0.f);
        bufA[m * 65 + nn] = a;
    }
    __syncthreads();
    if (t < 64) {
        float s = 0.f;
        for (int nn = 0; nn < 64; ++nn) s += bufA[t * 65 + nn];
        rsum[t] = fmaxf(s, 1e-6f);
    }
    __syncthreads();
    for (int e = t; e < 4096; e += 256) {
        const int m = e >> 6, nn = e & 63;
        bufA[m * 65 + nn] /= rsum[m];
    }
    __syncthreads();

    for (int e = t; e < 4096; e += 256) {
        const int nn = e >> 6, ee = e & 63;
        float a = 0.f;
        for (int d = 0; d < 64; d += 4) {
            const float4 wv4 = *(const float4*)&wg1[ee * 64 + d];
            a = fmaf(wv4.x, h0x[nn * 65 + d + 0], fmaf(wv4.y, h0x[nn * 65 + d + 1],
                fmaf(wv4.z, h0x[nn * 65 + d + 2], fmaf(wv4.w, h0x[nn * 65 + d + 3], a))));
        }
        bufT[nn * 65 + ee] = a;
    }
    __syncthreads();
    for (int e = t; e < 4096; e += 256) {
        const int m = e >> 6, ee = e & 63;
        float a = 0.f;
        for (int nn = 0; nn < 64; ++nn) a = fmaf(bufA[m * 65 + nn], bufT[nn * 65 + ee], a);
        h0x[m * 65 + ee] = fmaxf(a, 0.f);
    }
    __syncthreads();
    for (int e = t; e < 4096; e += 256) {
        const int nn = e >> 6, ee = e & 63;
        float a = 0.f;
        for (int d = 0; d < 64; d += 4) {
            const float4 wv4 = *(const float4*)&wg2[ee * 64 + d];
            a = fmaf(wv4.x, h0x[nn * 65 + d + 0], fmaf(wv4.y, h0x[nn * 65 + d + 1],
                fmaf(wv4.z, h0x[nn * 65 + d + 2], fmaf(wv4.w, h0x[nn * 65 + d + 3], a))));
        }
        bufT[nn * 65 + ee] = a;
    }
    __syncthreads();
    for (int e = t; e < 4096; e += 256) {
        const int m = e >> 6, ee = e & 63;
        float a = 0.f;
        for (int nn = 0; nn < 64; ++nn) a = fmaf(bufA[m * 65 + nn], bufT[nn * 65 + ee], a);
        a = fmaxf(a, 0.f);
        h0x[m * 65 + ee] = a;
        HgOut[((size_t)b * MM + m) * DD + ee] = a;
    }
    __syncthreads();
    // HgPk: fragment-packed bf16 (B-operand: cols m, k = d)
    for (int e = t; e < 4096; e += 256) {
        const int j = e & 7, l = (e >> 3) & 63, ks = (e >> 9) & 1, mb = e >> 10;
        const int m = mb * 16 + (l & 15);
        const int g = l >> 4;
        const int km = (j < 4) ? g * 4 + j : 16 + g * 4 + (j - 4);
        HgPk[(size_t)b * 4096 + e] = f2bf(h0x[m * 65 + ks * 32 + km]);
    }
}

// ---------------------------------------------------------------------------
// Kernel G: Gpk fragment-packed bf16 of G[m][c] = sum_d Hg[m][d] wn2t[c][d].
// grid (M, B), block 256.
// ---------------------------------------------------------------------------
__global__ __launch_bounds__(256) void k_gmat(
    const float* __restrict__ Hg, const float* __restrict__ wn2t,
    unsigned short* __restrict__ Gpk)
{
    const int m = blockIdx.x, b = blockIdx.y, c = threadIdx.x;
    __shared__ float hg[64];
    if (c < 64) hg[c] = Hg[((size_t)b * MM + m) * DD + c];
    __syncthreads();
    float a = 0.f;
#pragma unroll
    for (int d = 0; d < 64; d += 4) {
        const float4 wv4 = *(const float4*)&wn2t[c * DD + d];
        a = fmaf(wv4.x, hg[d + 0], fmaf(wv4.y, hg[d + 1], fmaf(wv4.z, hg[d + 2], fmaf(wv4.w, hg[d + 3], a))));
    }
    const int cb = c >> 4, c16 = c & 15;
    const int ks = m >> 5, km = m & 31;
    const int g = (km < 16) ? (km >> 2) : ((km - 16) >> 2);
    const int j = (km < 16) ? (km & 3) : 4 + ((km - 16) & 3);
    Gpk[(size_t)b * 16384 + ((cb * 2 + ks) * 64 + g * 16 + c16) * 8 + j] = f2bf(a);
}

// ---------------------------------------------------------------------------
// Kernel C (MFMA): logits -> softmax -> out = fmapH + attn @ G.
// grid (144, B), block 256 (wave = n-block). Residual read from bf16 fmapH.
// ---------------------------------------------------------------------------
__global__ __launch_bounds__(256) void k_inject(
    const unsigned short* __restrict__ fmapH, const unsigned short* __restrict__ projPk,
    const unsigned short* __restrict__ HgPk, const unsigned short* __restrict__ Gpk,
    float* __restrict__ out)
{
    __shared__ unsigned short attnL[64 * 72];

    const int b = blockIdx.y;
    const int tile = blockIdx.x;
    const int p0 = tile * 64;
    const int t = threadIdx.x;
    const int nb = t >> 6, l = t & 63;
    const int g = l >> 4, c16 = l & 15;

    const bf16x8* pp = (const bf16x8*)(projPk + (size_t)b * PPB);
    bf16x8 atok[2];
    atok[0] = pp[((tile * 4 + nb) * 2 + 0) * 64 + l];
    atok[1] = pp[((tile * 4 + nb) * 2 + 1) * 64 + l];

    const bf16x8* hp = (const bf16x8*)(HgPk + (size_t)b * 4096);
    f32x4 accL[4] = {};
#pragma unroll
    for (int ks = 0; ks < 2; ++ks)
#pragma unroll
        for (int mb = 0; mb < 4; ++mb)
            accL[mb] = __builtin_amdgcn_mfma_f32_16x16x32_bf16(atok[ks], hp[(mb * 2 + ks) * 64 + l], accL[mb], 0, 0, 0);

#pragma unroll
    for (int mb = 0; mb < 4; ++mb)
#pragma unroll
        for (int r = 0; r < 4; ++r) accL[mb][r] *= 0.125f;

    float mx[4], sm[4], inv[4];
#pragma unroll
    for (int r = 0; r < 4; ++r)
        mx[r] = fmaxf(fmaxf(accL[0][r], accL[1][r]), fmaxf(accL[2][r], accL[3][r]));
#pragma unroll
    for (int st = 1; st < 16; st <<= 1)
#pragma unroll
        for (int r = 0; r < 4; ++r) mx[r] = fmaxf(mx[r], __shfl_xor(mx[r], st, 64));
#pragma unroll
    for (int r = 0; r < 4; ++r) sm[r] = 0.f;
#pragma unroll
    for (int mb = 0; mb < 4; ++mb)
#pragma unroll
        for (int r = 0; r < 4; ++r) {
            const float e = __expf(accL[mb][r] - mx[r]);
            accL[mb][r] = e; sm[r] += e;
        }
#pragma unroll
    for (int st = 1; st < 16; st <<= 1)
#pragma unroll
        for (int r = 0; r < 4; ++r) sm[r] += __shfl_xor(sm[r], st, 64);
#pragma unroll
    for (int r = 0; r < 4; ++r) inv[r] = 1.f / sm[r];

#pragma unroll
    for (int mb = 0; mb < 4; ++mb)
#pragma unroll
        for (int r = 0; r < 4; ++r)
            attnL[(nb * 16 + g * 4 + r) * 72 + mb * 16 + c16] = f2bf(accL[mb][r] * inv[r]);
    __syncthreads();

    // attn fragment: lane l holds attn[row n = nb*16 + (l&15)][k = kmap(g,j)]
    const int nrow = nb * 16 + c16;
    bf16x8 battn[2];
#pragma unroll
    for (int ks = 0; ks < 2; ++ks) {
        const ushort4 lo = *(const ushort4*)&attnL[nrow * 72 + ks * 32 + g * 4];
        const ushort4 hi = *(const ushort4*)&attnL[nrow * 72 + ks * 32 + 16 + g * 4];
        bf16x8 f;
        f[0] = (short)lo.x; f[1] = (short)lo.y; f[2] = (short)lo.z; f[3] = (short)lo.w;
        f[4] = (short)hi.x; f[5] = (short)hi.y; f[6] = (short)hi.z; f[7] = (short)hi.w;
        battn[ks] = f;
    }

    // phase 3: attn as A (rows n), Gpk as B (cols c) -> D[n][c], n on reg axis
    const bf16x8* gp = (const bf16x8*)(Gpk + (size_t)b * 16384);
    const unsigned short* fHb = fmapH + (size_t)b * CC * HWP;
    float* ob = out + (size_t)b * CC * HWP;
    const int ncol = p0 + nb * 16 + g * 4;

#pragma unroll
    for (int cb = 0; cb < 16; ++cb) {
        f32x4 acc = {};
#pragma unroll
        for (int ks = 0; ks < 2; ++ks)
            acc = __builtin_amdgcn_mfma_f32_16x16x32_bf16(battn[ks], gp[(cb * 2 + ks) * 64 + l], acc, 0, 0, 0);
        const size_t off = (size_t)(cb * 16 + c16) * HWP + ncol;
        const s16x4 h4 = *(const s16x4*)&fHb[off];
        float4 o4;
        o4.x = bf2f((unsigned short)h4[0]) + acc[0];
        o4.y = bf2f((unsigned short)h4[1]) + acc[1];
        o4.z = bf2f((unsigned short)h4[2]) + acc[2];
        o4.w = bf2f((unsigned short)h4[3]) + acc[3];
        *(float4*)&ob[off] = o4;
    }
}

// ---------------------------------------------------------------------------
extern "C" void kernel_launch(void* const* d_in, const int* in_sizes, int n_in,
                              void* d_out, int out_size, void* d_ws, size_t ws_size,
                              hipStream_t stream)
{
    const float* fmap = (const float*)d_in[0];
    const float* ws1  = (const float*)d_in[1];
    const float* bs1  = (const float*)d_in[2];
    const float* ws2  = (const float*)d_in[3];
    const float* bs2  = (const float*)d_in[4];
    const float* wt2n = (const float*)d_in[5];
    const float* wn2t = (const float*)d_in[6];
    const float* wg1  = (const float*)d_in[7];
    const float* wg2  = (const float*)d_in[8];
    float* out = (float*)d_out;

    char* ws = (char*)d_ws;
    float*          scores = (float*)(ws + WS_SCORES_B);
    unsigned short* projPk = (unsigned short*)(ws + WS_PROJ_B);
    float*          HgW    = (float*)(ws + WS_HG_B);
    unsigned short* HgPk   = (unsigned short*)(ws + WS_HGPK_B);
    unsigned short* Gpk    = (unsigned short*)(ws + WS_GPK_B);
    unsigned short* wpk    = (unsigned short*)(ws + WS_WPK_B);
    unsigned short* fmapH  = (unsigned short*)(ws + WS_FMAPH_B);

    const dim3 blk(256);
    k_prep<<<dim3(128), blk, 0, stream>>>(ws1, wt2n, wpk);
    k_mfma_a<<<dim3(HWP / 64, BB), blk, 0, stream>>>(fmap, wpk, bs1, ws2, bs2, scores, projPk, fmapH);
    k_graph<<<dim3(BB), blk, 0, stream>>>(scores, projPk, wg1, wg2, HgW, HgPk);
    k_gmat<<<dim3(MM, BB), blk, 0, stream>>>(HgW, wn2t, Gpk);
    k_inject<<<dim3(HWP / 64, BB), blk, 0, stream>>>(fmapH, projPk, HgPk, Gpk, out);
}

// Round 8
// 185.688 us; speedup vs baseline: 1.0318x; 1.0318x over previous
//
#include <hip/hip_runtime.h>
#include <hip/hip_bf16.h>
#include <math.h>

#define BB 16
#define CC 256
#define HWP 9216
#define DD 64
#define MM 64

typedef __attribute__((ext_vector_type(8))) short bf16x8;
typedef __attribute__((ext_vector_type(4))) short s16x4;
typedef __attribute__((ext_vector_type(4))) float f32x4;

__device__ inline unsigned short f2bf(float f) {
    __hip_bfloat16 h = __float2bfloat16(f);
    return *reinterpret_cast<unsigned short*>(&h);
}
__device__ inline float bf2f(unsigned short h) {
    return __uint_as_float(((unsigned)h) << 16);
}

// workspace layout (bytes)
#define WS_SCORES_B 0u                    // fp32 16*9216*4        = 589824
#define WS_PROJ_B   589824u               // bf16 packed 16*589824 halfs = 18874368 B
#define WS_HG_B     19464192u             // fp32 16*64*64*4       = 262144
#define WS_HGPK_B   19726336u             // bf16 16*4096*2        = 131072
#define WS_GPK_B    19857408u             // bf16 16*16384*2       = 524288
#define WS_WPK_B    20381696u             // bf16 packed W, 65536

#define PPB 589824u   // projPk halfs per batch: 144*4*2*64*8

// k index bijection used by ALL fragments (HW-verified rounds 2-7):
// kmap(g, j) = j<4 ? g*4+j : 16+g*4+(j-4)
// A-frag: lane l holds A[row = l&15][k = kmap(l>>4, j)]
// B-frag: lane l holds B[col = l&15][k = kmap(l>>4, j)]
// D: lane l holds D[row = (l>>4)*4 + r][col = l&15]

// ---------------------------------------------------------------------------
// Prep: pack W = [ws1 (64,256); wt2n (64,256)] into per-lane MFMA A-fragment
// order. Layout: wpk[((obg*8 + ks)*64 + lane)*8 + j]. grid 128 x 256.
// ---------------------------------------------------------------------------
__global__ __launch_bounds__(256) void k_prep(
    const float* __restrict__ ws1, const float* __restrict__ wt2n,
    unsigned short* __restrict__ wpk)
{
    const int tid = blockIdx.x * 256 + threadIdx.x;     // 0..32767
    const int i  = tid & 7;
    const int l  = (tid >> 3) & 63;
    const int ks = (tid >> 9) & 7;
    const int ob = tid >> 12;                           // obg 0..7
    const int o = ob * 16 + (l & 15);
    const int g = l >> 4;
    const int k = ks * 32 + (i < 4 ? 4 * g + i : 16 + 4 * g + (i - 4));
    const float v = (o < 64) ? ws1[o * CC + k] : wt2n[(o - 64) * CC + k];
    wpk[tid] = f2bf(v);
}

// ---------------------------------------------------------------------------
// Kernel A (MFMA): D[128][64] = W * F per 64-position tile.
// LDS layout permuted so each B-fragment is one aligned ds_read_b128:
//   channel c -> p(c) = (c>>5)*32 + (((c>>2)&3)*8) + ((c>>4)&1)*4 + (c&3)
//   row byte = (n*272 + p)*2  XOR  ((n&7)<<4)     (bank spread)
// grid (144, B), block 256 (4 waves). Wave w computes obg {2w, 2w+1}.
// Waves 0,1 -> hid/scores; waves 2,3 -> proj fragment-packed.
// ---------------------------------------------------------------------------
#define LP 272   // LDS row pitch in halfs (544 B = 34*16: b128-aligned rows)

__global__ __launch_bounds__(256) void k_mfma_a(
    const float* __restrict__ fmap, const unsigned short* __restrict__ wpk,
    const float* __restrict__ bs1, const float* __restrict__ ws2,
    const float* __restrict__ bs2,
    float* __restrict__ scores, unsigned short* __restrict__ projPk)
{
    __shared__ unsigned short fL[64 * LP];   // 34816 B
    __shared__ float scoreP[8 * 64];

    const int b = blockIdx.y;
    const int tile = blockIdx.x;
    const int p0 = tile * 64;
    const int t = threadIdx.x;
    const int w = t >> 6, l = t & 63;
    const int g = l >> 4, c16 = l & 15;

    // A-frag prefetch: wave w owns obg {2w, 2w+1}; 16 x dwordx4 from L2
    const bf16x8* wp = (const bf16x8*)wpk;
    bf16x8 afr[2][8];
#pragma unroll
    for (int ob = 0; ob < 2; ++ob) {
        const int obg = w * 2 + ob;
#pragma unroll
        for (int ks = 0; ks < 8; ++ks) afr[ob][ks] = wp[(obg * 8 + ks) * 64 + l];
    }

    // stage fmap tile -> LDS bf16, permuted channel order
    const float* fb = fmap + (size_t)b * CC * HWP + p0;
    const int n0 = (t & 15) * 4;
    const int cbase = (t >> 4) * 4;          // 0..60
#pragma unroll
    for (int iter = 0; iter < 4; ++iter) {
        const int c0 = iter * 64 + cbase;
        const int within = c0 & 31;
        const int pp = (c0 >> 5) * 32 + ((within >> 2) & 3) * 8 + (within >> 4) * 4;
        float4 v0 = *(const float4*)&fb[(size_t)(c0 + 0) * HWP + n0];
        float4 v1 = *(const float4*)&fb[(size_t)(c0 + 1) * HWP + n0];
        float4 v2 = *(const float4*)&fb[(size_t)(c0 + 2) * HWP + n0];
        float4 v3 = *(const float4*)&fb[(size_t)(c0 + 3) * HWP + n0];
#pragma unroll
        for (int i = 0; i < 4; ++i) {
            const int n = n0 + i;
            const float a0 = (i == 0) ? v0.x : (i == 1) ? v0.y : (i == 2) ? v0.z : v0.w;
            const float a1 = (i == 0) ? v1.x : (i == 1) ? v1.y : (i == 2) ? v1.z : v1.w;
            const float a2 = (i == 0) ? v2.x : (i == 1) ? v2.y : (i == 2) ? v2.z : v2.w;
            const float a3 = (i == 0) ? v3.x : (i == 1) ? v3.y : (i == 2) ? v3.z : v3.w;
            s16x4 o;
            o[0] = (short)f2bf(a0); o[1] = (short)f2bf(a1);
            o[2] = (short)f2bf(a2); o[3] = (short)f2bf(a3);
            const unsigned byteoff = (unsigned)((n * LP + pp) * 2) ^ ((n & 7) << 4);
            *(s16x4*)((char*)fL + byteoff) = o;
        }
    }
    __syncthreads();

    f32x4 acc[2][4] = {};

#pragma unroll
    for (int ks = 0; ks < 8; ++ks) {
        bf16x8 bfr[4];
#pragma unroll
        for (int nb = 0; nb < 4; ++nb) {
            const int n = nb * 16 + c16;
            const unsigned byteoff =
                (unsigned)((n * LP + ks * 32 + g * 8) * 2) ^ ((n & 7) << 4);
            bfr[nb] = *(const bf16x8*)((const char*)fL + byteoff);
        }
#pragma unroll
        for (int ob = 0; ob < 2; ++ob)
#pragma unroll
            for (int nb = 0; nb < 4; ++nb)
                acc[ob][nb] = __builtin_amdgcn_mfma_f32_16x16x32_bf16(
                    afr[ob][ks], bfr[nb], acc[ob][nb], 0, 0, 0);
    }

    // epilogue. D element: row o_loc = g*4 + r, col n_loc = c16 (per nb).
    if (w < 2) {
        float sp[4] = {0.f, 0.f, 0.f, 0.f};
#pragma unroll
        for (int ob = 0; ob < 2; ++ob) {
            const int obase = w * 32 + ob * 16 + g * 4;
#pragma unroll
            for (int r = 0; r < 4; ++r) {
                const int o = obase + r;
                const float b1 = bs1[o], w2 = ws2[o];
#pragma unroll
                for (int nb = 0; nb < 4; ++nb) {
                    const float h = acc[ob][nb][r] + b1;
                    sp[nb] += w2 * fmaxf(h, 0.f);
                }
            }
        }
        const int gw = w * 4 + g;
#pragma unroll
        for (int nb = 0; nb < 4; ++nb) scoreP[gw * 64 + nb * 16 + c16] = sp[nb];
    } else {
        // proj rows: wave 2 -> obg {4,5} (ks=0), wave 3 -> obg {6,7} (ks=1)
        const int ks = w - 2;
        unsigned short* pb = projPk + (size_t)b * PPB;
#pragma unroll
        for (int nb = 0; nb < 4; ++nb) {
            bf16x8 pk;
#pragma unroll
            for (int r = 0; r < 4; ++r) {
                pk[r]     = (short)f2bf(acc[0][nb][r]);
                pk[4 + r] = (short)f2bf(acc[1][nb][r]);
            }
            *(bf16x8*)&pb[(size_t)(((tile * 4 + nb) * 2 + ks) * 64 + l) * 8] = pk;
        }
    }
    __syncthreads();
    if (t < 64) {
        float s = bs2[0];
#pragma unroll
        for (int gw = 0; gw < 8; ++gw) s += scoreP[gw * 64 + t];
        scores[b * HWP + p0 + t] = s;
    }
}

// ---------------------------------------------------------------------------
// Kernel B: radix-select top-64 (4 per-wave sub-histograms) + cosine
// adjacency + 2-layer GCN. grid (B), block 256.
// ---------------------------------------------------------------------------
__global__ __launch_bounds__(256) void k_graph(
    const float* __restrict__ scores, const unsigned short* __restrict__ projPk,
    const float* __restrict__ wg1, const float* __restrict__ wg2,
    float* __restrict__ HgOut, unsigned short* __restrict__ HgPk)
{
    __shared__ float h0x[64 * 65];
    __shared__ float bufA[64 * 65];
    __shared__ float bufT[64 * 65];
    __shared__ int hist4[1024];          // 4 sub-histograms (one per wave)
    __shared__ int idxL[64];
    __shared__ int eqIdx[64];
    __shared__ int sInts[8];
    __shared__ float norms[64], rsum[64];

    const int b = blockIdx.x;
    const int t = threadIdx.x;
    const int wv = t >> 6;

    unsigned uv[36];
#pragma unroll
    for (int i = 0; i < 36; ++i) {
        const unsigned u = __float_as_uint(scores[b * HWP + i * 256 + t]);
        uv[i] = (u >> 31) ? ~u : (u | 0x80000000u);
    }

    unsigned prefix = 0;
    int need = 64;
    for (int pass = 0; pass < 4; ++pass) {
        const int shift = 24 - 8 * pass;
#pragma unroll
        for (int i = 0; i < 4; ++i) hist4[t + 256 * i] = 0;
        __syncthreads();
#pragma unroll
        for (int i = 0; i < 36; ++i) {
            const bool ok = (pass == 0) || ((uv[i] >> (shift + 8)) == prefix);
            if (ok) atomicAdd(&hist4[(wv << 8) + ((uv[i] >> shift) & 255)], 1);
        }
        __syncthreads();
        if (t < 64) {
            const int l = t;
            int h0 = 0, h1 = 0, h2 = 0, h3 = 0;
#pragma unroll
            for (int i = 0; i < 4; ++i) {
                h0 += hist4[i * 256 + 4 * l + 0];
                h1 += hist4[i * 256 + 4 * l + 1];
                h2 += hist4[i * 256 + 4 * l + 2];
                h3 += hist4[i * 256 + 4 * l + 3];
            }
            const int T = h0 + h1 + h2 + h3;
            int S = T;
            for (int st = 1; st < 64; st <<= 1) {
                const int v = __shfl_down(S, st, 64);
                if (l + st < 64) S += v;
            }
            const int Sexc = S - T;
            const int ge3 = Sexc + h3, ge2 = ge3 + h2, ge1 = ge2 + h1, ge0 = ge1 + h0;
            if (ge3 - h3 < need && need <= ge3) { sInts[0] = 4 * l + 3; sInts[1] = ge3 - h3; }
            if (ge2 - h2 < need && need <= ge2) { sInts[0] = 4 * l + 2; sInts[1] = ge2 - h2; }
            if (ge1 - h1 < need && need <= ge1) { sInts[0] = 4 * l + 1; sInts[1] = ge1 - h1; }
            if (ge0 - h0 < need && need <= ge0) { sInts[0] = 4 * l + 0; sInts[1] = ge0 - h0; }
        }
        __syncthreads();
        prefix = (prefix << 8) | (unsigned)sInts[0];
        need -= sInts[1];
        __syncthreads();
    }

    if (t == 0) { sInts[2] = 0; sInts[3] = 0; }
    __syncthreads();
    const unsigned P = prefix;
    const int needEq = need;
#pragma unroll
    for (int i = 0; i < 36; ++i) {
        const unsigned u = uv[i];
        const int idx = i * 256 + t;
        if (u > P) { const int p = atomicAdd(&sInts[2], 1); idxL[p] = idx; }
        else if (u == P) { const int p = atomicAdd(&sInts[3], 1); if (p < 64) eqIdx[p] = idx; }
    }
    __syncthreads();
    if (t == 0) {
        int ec = sInts[3]; if (ec > 64) ec = 64;
        const int base = sInts[2];
        for (int k2 = 0; k2 < needEq; ++k2) {
            int mn = 0x7FFFFFFF, mi = 0;
            for (int j = 0; j < ec; ++j) if (eqIdx[j] < mn) { mn = eqIdx[j]; mi = j; }
            idxL[base + k2] = mn; eqIdx[mi] = 0x7FFFFFFF;
        }
    }
    __syncthreads();

    // gather H0[m][d] from fragment-packed proj
    const unsigned short* pb = projPk + (size_t)b * PPB;
    for (int e = t; e < 4096; e += 256) {
        const int m = e >> 6, d = e & 63;
        const int idx = idxL[m];
        const int tile = idx >> 6, nl = idx & 63;
        const int nb = nl >> 4, c16 = nl & 15;
        const int ks = d >> 5, dm = d & 31;
        const int gg = (dm & 15) >> 2;
        const int j = (dm & 3) + ((dm >= 16) ? 4 : 0);
        h0x[m * 65 + d] = bf2f(pb[(size_t)((((tile * 4 + nb) * 2 + ks) * 64 + gg * 16 + c16) * 8 + j)]);
    }
    __syncthreads();

    if (t < 64) {
        float s = 0.f;
        for (int d = 0; d < 64; ++d) { const float v = h0x[t * 65 + d]; s = fmaf(v, v, s); }
        norms[t] = fmaxf(sqrtf(s), 1e-6f);
    }
    __syncthreads();

    for (int e = t; e < 4096; e += 256) {
        const int m = e >> 6, nn = e & 63;
        float a = 0.f;
        for (int d = 0; d < 64; ++d) a = fmaf(h0x[m * 65 + d], h0x[nn * 65 + d], a);
        a = fmaxf(a / (norms[m] * norms[nn]), 0.f) + (m == nn ? 1.f : 0.f);
        bufA[m * 65 + nn] = a;
    }
    __syncthreads();
    if (t < 64) {
        float s = 0.f;
        for (int nn = 0; nn < 64; ++nn) s += bufA[t * 65 + nn];
        rsum[t] = fmaxf(s, 1e-6f);
    }
    __syncthreads();
    for (int e = t; e < 4096; e += 256) {
        const int m = e >> 6, nn = e & 63;
        bufA[m * 65 + nn] /= rsum[m];
    }
    __syncthreads();

    for (int e = t; e < 4096; e += 256) {
        const int nn = e >> 6, ee = e & 63;
        float a = 0.f;
        for (int d = 0; d < 64; d += 4) {
            const float4 wv4 = *(const float4*)&wg1[ee * 64 + d];
            a = fmaf(wv4.x, h0x[nn * 65 + d + 0], fmaf(wv4.y, h0x[nn * 65 + d + 1],
                fmaf(wv4.z, h0x[nn * 65 + d + 2], fmaf(wv4.w, h0x[nn * 65 + d + 3], a))));
        }
        bufT[nn * 65 + ee] = a;
    }
    __syncthreads();
    for (int e = t; e < 4096; e += 256) {
        const int m = e >> 6, ee = e & 63;
        float a = 0.f;
        for (int nn = 0; nn < 64; ++nn) a = fmaf(bufA[m * 65 + nn], bufT[nn * 65 + ee], a);
        h0x[m * 65 + ee] = fmaxf(a, 0.f);
    }
    __syncthreads();
    for (int e = t; e < 4096; e += 256) {
        const int nn = e >> 6, ee = e & 63;
        float a = 0.f;
        for (int d = 0; d < 64; d += 4) {
            const float4 wv4 = *(const float4*)&wg2[ee * 64 + d];
            a = fmaf(wv4.x, h0x[nn * 65 + d + 0], fmaf(wv4.y, h0x[nn * 65 + d + 1],
                fmaf(wv4.z, h0x[nn * 65 + d + 2], fmaf(wv4.w, h0x[nn * 65 + d + 3], a))));
        }
        bufT[nn * 65 + ee] = a;
    }
    __syncthreads();
    for (int e = t; e < 4096; e += 256) {
        const int m = e >> 6, ee = e & 63;
        float a = 0.f;
        for (int nn = 0; nn < 64; ++nn) a = fmaf(bufA[m * 65 + nn], bufT[nn * 65 + ee], a);
        a = fmaxf(a, 0.f);
        h0x[m * 65 + ee] = a;
        HgOut[((size_t)b * MM + m) * DD + ee] = a;
    }
    __syncthreads();
    // HgPk: fragment-packed bf16 (B-operand: cols m, k = d)
    for (int e = t; e < 4096; e += 256) {
        const int j = e & 7, l = (e >> 3) & 63, ks = (e >> 9) & 1, mb = e >> 10;
        const int m = mb * 16 + (l & 15);
        const int g = l >> 4;
        const int km = (j < 4) ? g * 4 + j : 16 + g * 4 + (j - 4);
        HgPk[(size_t)b * 4096 + e] = f2bf(h0x[m * 65 + ks * 32 + km]);
    }
}

// ---------------------------------------------------------------------------
// Kernel G: Gpk fragment-packed bf16 of G[m][c] = sum_d Hg[m][d] wn2t[c][d].
// grid (M, B), block 256.
// ---------------------------------------------------------------------------
__global__ __launch_bounds__(256) void k_gmat(
    const float* __restrict__ Hg, const float* __restrict__ wn2t,
    unsigned short* __restrict__ Gpk)
{
    const int m = blockIdx.x, b = blockIdx.y, c = threadIdx.x;
    __shared__ float hg[64];
    if (c < 64) hg[c] = Hg[((size_t)b * MM + m) * DD + c];
    __syncthreads();
    float a = 0.f;
#pragma unroll
    for (int d = 0; d < 64; d += 4) {
        const float4 wv4 = *(const float4*)&wn2t[c * DD + d];
        a = fmaf(wv4.x, hg[d + 0], fmaf(wv4.y, hg[d + 1], fmaf(wv4.z, hg[d + 2], fmaf(wv4.w, hg[d + 3], a))));
    }
    const int cb = c >> 4, c16 = c & 15;
    const int ks = m >> 5, km = m & 31;
    const int g = (km < 16) ? (km >> 2) : ((km - 16) >> 2);
    const int j = (km < 16) ? (km & 3) : 4 + ((km - 16) & 3);
    Gpk[(size_t)b * 16384 + ((cb * 2 + ks) * 64 + g * 16 + c16) * 8 + j] = f2bf(a);
}

// ---------------------------------------------------------------------------
// Kernel C (MFMA): logits -> softmax -> out = fmap + attn @ G.
// grid (144, B), block 256 (wave = n-block).
// Phase 3: attn as A (rows n), Gpk as B (cols c) -> D[n][c]; residual fmap
// loads for ALL 16 cb issued up-front into registers (T14 async-stage) so
// L3 latency hides under the 32 PV MFMAs.
// ---------------------------------------------------------------------------
__global__ __launch_bounds__(256) void k_inject(
    const float* __restrict__ fmap, const unsigned short* __restrict__ projPk,
    const unsigned short* __restrict__ HgPk, const unsigned short* __restrict__ Gpk,
    float* __restrict__ out)
{
    __shared__ unsigned short attnL[64 * 72];

    const int b = blockIdx.y;
    const int tile = blockIdx.x;
    const int p0 = tile * 64;
    const int t = threadIdx.x;
    const int nb = t >> 6, l = t & 63;
    const int g = l >> 4, c16 = l & 15;

    const bf16x8* pp = (const bf16x8*)(projPk + (size_t)b * PPB);
    bf16x8 atok[2];
    atok[0] = pp[((tile * 4 + nb) * 2 + 0) * 64 + l];
    atok[1] = pp[((tile * 4 + nb) * 2 + 1) * 64 + l];

    const bf16x8* hp = (const bf16x8*)(HgPk + (size_t)b * 4096);
    f32x4 accL[4] = {};
#pragma unroll
    for (int ks = 0; ks < 2; ++ks)
#pragma unroll
        for (int mb = 0; mb < 4; ++mb)
            accL[mb] = __builtin_amdgcn_mfma_f32_16x16x32_bf16(atok[ks], hp[(mb * 2 + ks) * 64 + l], accL[mb], 0, 0, 0);

#pragma unroll
    for (int mb = 0; mb < 4; ++mb)
#pragma unroll
        for (int r = 0; r < 4; ++r) accL[mb][r] *= 0.125f;

    float mx[4], sm[4], inv[4];
#pragma unroll
    for (int r = 0; r < 4; ++r)
        mx[r] = fmaxf(fmaxf(accL[0][r], accL[1][r]), fmaxf(accL[2][r], accL[3][r]));
#pragma unroll
    for (int st = 1; st < 16; st <<= 1)
#pragma unroll
        for (int r = 0; r < 4; ++r) mx[r] = fmaxf(mx[r], __shfl_xor(mx[r], st, 64));
#pragma unroll
    for (int r = 0; r < 4; ++r) sm[r] = 0.f;
#pragma unroll
    for (int mb = 0; mb < 4; ++mb)
#pragma unroll
        for (int r = 0; r < 4; ++r) {
            const float e = __expf(accL[mb][r] - mx[r]);
            accL[mb][r] = e; sm[r] += e;
        }
#pragma unroll
    for (int st = 1; st < 16; st <<= 1)
#pragma unroll
        for (int r = 0; r < 4; ++r) sm[r] += __shfl_xor(sm[r], st, 64);
#pragma unroll
    for (int r = 0; r < 4; ++r) inv[r] = 1.f / sm[r];

#pragma unroll
    for (int mb = 0; mb < 4; ++mb)
#pragma unroll
        for (int r = 0; r < 4; ++r)
            attnL[(nb * 16 + g * 4 + r) * 72 + mb * 16 + c16] = f2bf(accL[mb][r] * inv[r]);

    // T14: issue residual fmap loads (16 x float4) BEFORE the barrier + PV
    // MFMAs; compile-time-indexed res[] stays in VGPRs.
    const float* fb = fmap + (size_t)b * CC * HWP;
    float* ob = out + (size_t)b * CC * HWP;
    const int ncol = p0 + nb * 16 + g * 4;
    float4 res[16];
#pragma unroll
    for (int cb = 0; cb < 16; ++cb)
        res[cb] = *(const float4*)&fb[(size_t)(cb * 16 + c16) * HWP + ncol];

    __syncthreads();

    // attn fragment: lane l holds attn[row n = nb*16 + (l&15)][k = kmap(g,j)]
    const int nrow = nb * 16 + c16;
    bf16x8 battn[2];
#pragma unroll
    for (int ks = 0; ks < 2; ++ks) {
        const ushort4 lo = *(const ushort4*)&attnL[nrow * 72 + ks * 32 + g * 4];
        const ushort4 hi = *(const ushort4*)&attnL[nrow * 72 + ks * 32 + 16 + g * 4];
        bf16x8 f;
        f[0] = (short)lo.x; f[1] = (short)lo.y; f[2] = (short)lo.z; f[3] = (short)lo.w;
        f[4] = (short)hi.x; f[5] = (short)hi.y; f[6] = (short)hi.z; f[7] = (short)hi.w;
        battn[ks] = f;
    }

    const bf16x8* gp = (const bf16x8*)(Gpk + (size_t)b * 16384);
#pragma unroll
    for (int cb = 0; cb < 16; ++cb) {
        f32x4 acc = {};
#pragma unroll
        for (int ks = 0; ks < 2; ++ks)
            acc = __builtin_amdgcn_mfma_f32_16x16x32_bf16(battn[ks], gp[(cb * 2 + ks) * 64 + l], acc, 0, 0, 0);
        const size_t off = (size_t)(cb * 16 + c16) * HWP + ncol;
        float4 o4;
        o4.x = res[cb].x + acc[0];
        o4.y = res[cb].y + acc[1];
        o4.z = res[cb].z + acc[2];
        o4.w = res[cb].w + acc[3];
        *(float4*)&ob[off] = o4;
    }
}

// ---------------------------------------------------------------------------
extern "C" void kernel_launch(void* const* d_in, const int* in_sizes, int n_in,
                              void* d_out, int out_size, void* d_ws, size_t ws_size,
                              hipStream_t stream)
{
    const float* fmap = (const float*)d_in[0];
    const float* ws1  = (const float*)d_in[1];
    const float* bs1  = (const float*)d_in[2];
    const float* ws2  = (const float*)d_in[3];
    const float* bs2  = (const float*)d_in[4];
    const float* wt2n = (const float*)d_in[5];
    const float* wn2t = (const float*)d_in[6];
    const float* wg1  = (const float*)d_in[7];
    const float* wg2  = (const float*)d_in[8];
    float* out = (float*)d_out;

    char* ws = (char*)d_ws;
    float*          scores = (float*)(ws + WS_SCORES_B);
    unsigned short* projPk = (unsigned short*)(ws + WS_PROJ_B);
    float*          HgW    = (float*)(ws + WS_HG_B);
    unsigned short* HgPk   = (unsigned short*)(ws + WS_HGPK_B);
    unsigned short* Gpk    = (unsigned short*)(ws + WS_GPK_B);
    unsigned short* wpk    = (unsigned short*)(ws + WS_WPK_B);

    const dim3 blk(256);
    k_prep<<<dim3(128), blk, 0, stream>>>(ws1, wt2n, wpk);
    k_mfma_a<<<dim3(HWP / 64, BB), blk, 0, stream>>>(fmap, wpk, bs1, ws2, bs2, scores, projPk);
    k_graph<<<dim3(BB), blk, 0, stream>>>(scores, projPk, wg1, wg2, HgW, HgPk);
    k_gmat<<<dim3(MM, BB), blk, 0, stream>>>(HgW, wn2t, Gpk);
    k_inject<<<dim3(HWP / 64, BB), blk, 0, stream>>>(fmap, projPk, HgPk, Gpk, out);
}

// Round 9
// 143.477 us; speedup vs baseline: 1.3353x; 1.2942x over previous
//
#include <hip/hip_runtime.h>
#include <hip/hip_bf16.h>
#include <math.h>

#define BB 16
#define CC 256
#define HWP 9216
#define DD 64
#define MM 64

typedef __attribute__((ext_vector_type(8))) short bf16x8;
typedef __attribute__((ext_vector_type(4))) short s16x4;
typedef __attribute__((ext_vector_type(4))) float f32x4;

__device__ inline unsigned short f2bf(float f) {
    __hip_bfloat16 h = __float2bfloat16(f);
    return *reinterpret_cast<unsigned short*>(&h);
}
__device__ inline float bf2f(unsigned short h) {
    return __uint_as_float(((unsigned)h) << 16);
}

// workspace layout (bytes)
#define WS_SCORES_B 0u                    // fp32 16*9216*4        = 589824
#define WS_PROJ_B   589824u               // bf16 packed 16*589824 halfs = 18874368 B
#define WS_HG_B     19464192u             // (unused)
#define WS_HGPK_B   19726336u             // bf16 16*4096*2        = 131072
#define WS_GPK_B    19857408u             // bf16 16*16384*2       = 524288
#define WS_WPK_B    20381696u             // bf16 packed W, 65536

#define PPB 589824u   // projPk halfs per batch: 144*4*2*64*8

// k index bijection used by ALL fragments (HW-verified rounds 2-8):
// kmap(g, j) = j<4 ? g*4+j : 16+g*4+(j-4)
// A-frag: lane l holds A[row = l&15][k = kmap(l>>4, j)]
// B-frag: lane l holds B[col = l&15][k = kmap(l>>4, j)]
// D: lane l holds D[row = (l>>4)*4 + r][col = l&15]

// A-frag from fp32 matrix M stored [row][k] with pitch
__device__ inline bf16x8 fragA_f32(const float* M, int pitch, int row0, int ksBase, int l) {
    const int g = l >> 4, r = l & 15;
    bf16x8 f;
#pragma unroll
    for (int j = 0; j < 8; ++j) {
        const int km = (j < 4) ? 4 * g + j : 16 + 4 * g + (j - 4);
        f[j] = (short)f2bf(M[(row0 + r) * pitch + ksBase + km]);
    }
    return f;
}
// B-frag where B[col][k] = M[col*pitch + k]  (row-major [col][k])
__device__ inline bf16x8 fragB_row_f32(const float* M, int pitch, int col0, int ksBase, int l) {
    const int g = l >> 4, c = l & 15;
    bf16x8 f;
#pragma unroll
    for (int j = 0; j < 8; ++j) {
        const int km = (j < 4) ? 4 * g + j : 16 + 4 * g + (j - 4);
        f[j] = (short)f2bf(M[(col0 + c) * pitch + ksBase + km]);
    }
    return f;
}
// B-frag where B[col][k] = M[k*pitch + col]  (column read)
__device__ inline bf16x8 fragB_col_f32(const float* M, int pitch, int col0, int ksBase, int l) {
    const int g = l >> 4, c = l & 15;
    bf16x8 f;
#pragma unroll
    for (int j = 0; j < 8; ++j) {
        const int km = (j < 4) ? 4 * g + j : 16 + 4 * g + (j - 4);
        f[j] = (short)f2bf(M[(ksBase + km) * pitch + col0 + c]);
    }
    return f;
}

// ---------------------------------------------------------------------------
// Prep: pack W = [ws1 (64,256); wt2n (64,256)] into per-lane MFMA A-fragment
// order. Layout: wpk[((obg*8 + ks)*64 + lane)*8 + j]. grid 128 x 256.
// ---------------------------------------------------------------------------
__global__ __launch_bounds__(256) void k_prep(
    const float* __restrict__ ws1, const float* __restrict__ wt2n,
    unsigned short* __restrict__ wpk)
{
    const int tid = blockIdx.x * 256 + threadIdx.x;     // 0..32767
    const int i  = tid & 7;
    const int l  = (tid >> 3) & 63;
    const int ks = (tid >> 9) & 7;
    const int ob = tid >> 12;                           // obg 0..7
    const int o = ob * 16 + (l & 15);
    const int g = l >> 4;
    const int k = ks * 32 + (i < 4 ? 4 * g + i : 16 + 4 * g + (i - 4));
    const float v = (o < 64) ? ws1[o * CC + k] : wt2n[(o - 64) * CC + k];
    wpk[tid] = f2bf(v);
}

// ---------------------------------------------------------------------------
// Kernel A (MFMA): D[128][64] = W * F per 64-position tile. (unchanged R6)
// ---------------------------------------------------------------------------
#define LP 272   // LDS row pitch in halfs (544 B = 34*16: b128-aligned rows)

__global__ __launch_bounds__(256) void k_mfma_a(
    const float* __restrict__ fmap, const unsigned short* __restrict__ wpk,
    const float* __restrict__ bs1, const float* __restrict__ ws2,
    const float* __restrict__ bs2,
    float* __restrict__ scores, unsigned short* __restrict__ projPk)
{
    __shared__ unsigned short fL[64 * LP];   // 34816 B
    __shared__ float scoreP[8 * 64];

    const int b = blockIdx.y;
    const int tile = blockIdx.x;
    const int p0 = tile * 64;
    const int t = threadIdx.x;
    const int w = t >> 6, l = t & 63;
    const int g = l >> 4, c16 = l & 15;

    const bf16x8* wp = (const bf16x8*)wpk;
    bf16x8 afr[2][8];
#pragma unroll
    for (int ob = 0; ob < 2; ++ob) {
        const int obg = w * 2 + ob;
#pragma unroll
        for (int ks = 0; ks < 8; ++ks) afr[ob][ks] = wp[(obg * 8 + ks) * 64 + l];
    }

    const float* fb = fmap + (size_t)b * CC * HWP + p0;
    const int n0 = (t & 15) * 4;
    const int cbase = (t >> 4) * 4;          // 0..60
#pragma unroll
    for (int iter = 0; iter < 4; ++iter) {
        const int c0 = iter * 64 + cbase;
        const int within = c0 & 31;
        const int pp = (c0 >> 5) * 32 + ((within >> 2) & 3) * 8 + (within >> 4) * 4;
        float4 v0 = *(const float4*)&fb[(size_t)(c0 + 0) * HWP + n0];
        float4 v1 = *(const float4*)&fb[(size_t)(c0 + 1) * HWP + n0];
        float4 v2 = *(const float4*)&fb[(size_t)(c0 + 2) * HWP + n0];
        float4 v3 = *(const float4*)&fb[(size_t)(c0 + 3) * HWP + n0];
#pragma unroll
        for (int i = 0; i < 4; ++i) {
            const int n = n0 + i;
            const float a0 = (i == 0) ? v0.x : (i == 1) ? v0.y : (i == 2) ? v0.z : v0.w;
            const float a1 = (i == 0) ? v1.x : (i == 1) ? v1.y : (i == 2) ? v1.z : v1.w;
            const float a2 = (i == 0) ? v2.x : (i == 1) ? v2.y : (i == 2) ? v2.z : v2.w;
            const float a3 = (i == 0) ? v3.x : (i == 1) ? v3.y : (i == 2) ? v3.z : v3.w;
            s16x4 o;
            o[0] = (short)f2bf(a0); o[1] = (short)f2bf(a1);
            o[2] = (short)f2bf(a2); o[3] = (short)f2bf(a3);
            const unsigned byteoff = (unsigned)((n * LP + pp) * 2) ^ ((n & 7) << 4);
            *(s16x4*)((char*)fL + byteoff) = o;
        }
    }
    __syncthreads();

    f32x4 acc[2][4] = {};

#pragma unroll
    for (int ks = 0; ks < 8; ++ks) {
        bf16x8 bfr[4];
#pragma unroll
        for (int nb = 0; nb < 4; ++nb) {
            const int n = nb * 16 + c16;
            const unsigned byteoff =
                (unsigned)((n * LP + ks * 32 + g * 8) * 2) ^ ((n & 7) << 4);
            bfr[nb] = *(const bf16x8*)((const char*)fL + byteoff);
        }
#pragma unroll
        for (int ob = 0; ob < 2; ++ob)
#pragma unroll
            for (int nb = 0; nb < 4; ++nb)
                acc[ob][nb] = __builtin_amdgcn_mfma_f32_16x16x32_bf16(
                    afr[ob][ks], bfr[nb], acc[ob][nb], 0, 0, 0);
    }

    if (w < 2) {
        float sp[4] = {0.f, 0.f, 0.f, 0.f};
#pragma unroll
        for (int ob = 0; ob < 2; ++ob) {
            const int obase = w * 32 + ob * 16 + g * 4;
#pragma unroll
            for (int r = 0; r < 4; ++r) {
                const int o = obase + r;
                const float b1 = bs1[o], w2 = ws2[o];
#pragma unroll
                for (int nb = 0; nb < 4; ++nb) {
                    const float h = acc[ob][nb][r] + b1;
                    sp[nb] += w2 * fmaxf(h, 0.f);
                }
            }
        }
        const int gw = w * 4 + g;
#pragma unroll
        for (int nb = 0; nb < 4; ++nb) scoreP[gw * 64 + nb * 16 + c16] = sp[nb];
    } else {
        const int ks = w - 2;
        unsigned short* pb = projPk + (size_t)b * PPB;
#pragma unroll
        for (int nb = 0; nb < 4; ++nb) {
            bf16x8 pk;
#pragma unroll
            for (int r = 0; r < 4; ++r) {
                pk[r]     = (short)f2bf(acc[0][nb][r]);
                pk[4 + r] = (short)f2bf(acc[1][nb][r]);
            }
            *(bf16x8*)&pb[(size_t)(((tile * 4 + nb) * 2 + ks) * 64 + l) * 8] = pk;
        }
    }
    __syncthreads();
    if (t < 64) {
        float s = bs2[0];
#pragma unroll
        for (int gw = 0; gw < 8; ++gw) s += scoreP[gw * 64 + t];
        scores[b * HWP + p0 + t] = s;
    }
}

// ---------------------------------------------------------------------------
// Kernel B: radix-select top-64 + MFMA GCN + fused G-matrix pack.
// grid (B), block 256 (4 waves). All 64x64 matmuls via mfma_f32_16x16x32_bf16:
// wave w owns D rows w*16..w*16+15, 4 col-blocks, 2 k-steps.
// ---------------------------------------------------------------------------
__global__ __launch_bounds__(256) void k_graph(
    const float* __restrict__ scores, const unsigned short* __restrict__ projPk,
    const float* __restrict__ wg1, const float* __restrict__ wg2,
    const float* __restrict__ wn2t,
    unsigned short* __restrict__ HgPk, unsigned short* __restrict__ Gpk)
{
    __shared__ float h0x[64 * 65];       // H0 -> X -> Hg
    __shared__ float bufA[64 * 65];      // normalized adjacency
    __shared__ float bufT[64 * 65];      // T1 / T2 / G-chunk
    __shared__ int hist4[1024];
    __shared__ int idxL[64];
    __shared__ int eqIdx[64];
    __shared__ int sInts[8];
    __shared__ float norms[64], rsum[64];

    const int b = blockIdx.x;
    const int t = threadIdx.x;
    const int wv = t >> 6, lane = t & 63;
    const int lg = lane >> 4, c16 = lane & 15;

    // ---- top-64 radix select (unchanged) ----
    unsigned uv[36];
#pragma unroll
    for (int i = 0; i < 36; ++i) {
        const unsigned u = __float_as_uint(scores[b * HWP + i * 256 + t]);
        uv[i] = (u >> 31) ? ~u : (u | 0x80000000u);
    }

    unsigned prefix = 0;
    int need = 64;
    for (int pass = 0; pass < 4; ++pass) {
        const int shift = 24 - 8 * pass;
#pragma unroll
        for (int i = 0; i < 4; ++i) hist4[t + 256 * i] = 0;
        __syncthreads();
#pragma unroll
        for (int i = 0; i < 36; ++i) {
            const bool ok = (pass == 0) || ((uv[i] >> (shift + 8)) == prefix);
            if (ok) atomicAdd(&hist4[(wv << 8) + ((uv[i] >> shift) & 255)], 1);
        }
        __syncthreads();
        if (t < 64) {
            const int l = t;
            int h0 = 0, h1 = 0, h2 = 0, h3 = 0;
#pragma unroll
            for (int i = 0; i < 4; ++i) {
                h0 += hist4[i * 256 + 4 * l + 0];
                h1 += hist4[i * 256 + 4 * l + 1];
                h2 += hist4[i * 256 + 4 * l + 2];
                h3 += hist4[i * 256 + 4 * l + 3];
            }
            const int T = h0 + h1 + h2 + h3;
            int S = T;
            for (int st = 1; st < 64; st <<= 1) {
                const int v = __shfl_down(S, st, 64);
                if (l + st < 64) S += v;
            }
            const int Sexc = S - T;
            const int ge3 = Sexc + h3, ge2 = ge3 + h2, ge1 = ge2 + h1, ge0 = ge1 + h0;
            if (ge3 - h3 < need && need <= ge3) { sInts[0] = 4 * l + 3; sInts[1] = ge3 - h3; }
            if (ge2 - h2 < need && need <= ge2) { sInts[0] = 4 * l + 2; sInts[1] = ge2 - h2; }
            if (ge1 - h1 < need && need <= ge1) { sInts[0] = 4 * l + 1; sInts[1] = ge1 - h1; }
            if (ge0 - h0 < need && need <= ge0) { sInts[0] = 4 * l + 0; sInts[1] = ge0 - h0; }
        }
        __syncthreads();
        prefix = (prefix << 8) | (unsigned)sInts[0];
        need -= sInts[1];
        __syncthreads();
    }

    if (t == 0) { sInts[2] = 0; sInts[3] = 0; }
    __syncthreads();
    const unsigned P = prefix;
    const int needEq = need;
#pragma unroll
    for (int i = 0; i < 36; ++i) {
        const unsigned u = uv[i];
        const int idx = i * 256 + t;
        if (u > P) { const int p = atomicAdd(&sInts[2], 1); idxL[p] = idx; }
        else if (u == P) { const int p = atomicAdd(&sInts[3], 1); if (p < 64) eqIdx[p] = idx; }
    }
    __syncthreads();
    if (t == 0) {
        int ec = sInts[3]; if (ec > 64) ec = 64;
        const int base = sInts[2];
        for (int k2 = 0; k2 < needEq; ++k2) {
            int mn = 0x7FFFFFFF, mi = 0;
            for (int j = 0; j < ec; ++j) if (eqIdx[j] < mn) { mn = eqIdx[j]; mi = j; }
            idxL[base + k2] = mn; eqIdx[mi] = 0x7FFFFFFF;
        }
    }
    __syncthreads();

    // ---- gather H0[m][d] from fragment-packed proj ----
    const unsigned short* pb = projPk + (size_t)b * PPB;
    for (int e = t; e < 4096; e += 256) {
        const int m = e >> 6, d = e & 63;
        const int idx = idxL[m];
        const int tile = idx >> 6, nl = idx & 63;
        const int nb = nl >> 4, cc16 = nl & 15;
        const int ks = d >> 5, dm = d & 31;
        const int gg = (dm & 15) >> 2;
        const int j = (dm & 3) + ((dm >= 16) ? 4 : 0);
        h0x[m * 65 + d] = bf2f(pb[(size_t)((((tile * 4 + nb) * 2 + ks) * 64 + gg * 16 + cc16) * 8 + j)]);
    }
    __syncthreads();

    if (t < 64) {
        float s = 0.f;
        for (int d = 0; d < 64; ++d) { const float v = h0x[t * 65 + d]; s = fmaf(v, v, s); }
        norms[t] = fmaxf(sqrtf(s), 1e-6f);
    }
    __syncthreads();

    // ---- S = H0·H0^T (MFMA) -> bufA = relu(S/nn) + I ----
    {
        f32x4 dacc[4] = {};
#pragma unroll
        for (int ks = 0; ks < 2; ++ks) {
            const bf16x8 a = fragA_f32(h0x, 65, wv * 16, ks * 32, lane);
#pragma unroll
            for (int cb = 0; cb < 4; ++cb) {
                const bf16x8 bb = fragB_row_f32(h0x, 65, cb * 16, ks * 32, lane);
                dacc[cb] = __builtin_amdgcn_mfma_f32_16x16x32_bf16(a, bb, dacc[cb], 0, 0, 0);
            }
        }
#pragma unroll
        for (int cb = 0; cb < 4; ++cb)
#pragma unroll
            for (int r = 0; r < 4; ++r) {
                const int rr = wv * 16 + lg * 4 + r, ccol = cb * 16 + c16;
                float s = dacc[cb][r] / (norms[rr] * norms[ccol]);
                s = fmaxf(s, 0.f) + (rr == ccol ? 1.f : 0.f);
                bufA[rr * 65 + ccol] = s;
            }
    }
    __syncthreads();
    if (t < 64) {
        float s = 0.f;
        for (int nn = 0; nn < 64; ++nn) s += bufA[t * 65 + nn];
        rsum[t] = fmaxf(s, 1e-6f);
    }
    __syncthreads();
    for (int e = t; e < 4096; e += 256) {
        const int m = e >> 6, nn = e & 63;
        bufA[m * 65 + nn] /= rsum[m];
    }
    // ---- T1 = H0 @ wg1^T (MFMA, B from global wg1) -> bufT ----
    {
        f32x4 dacc[4] = {};
#pragma unroll
        for (int ks = 0; ks < 2; ++ks) {
            const bf16x8 a = fragA_f32(h0x, 65, wv * 16, ks * 32, lane);
#pragma unroll
            for (int cb = 0; cb < 4; ++cb) {
                const bf16x8 bb = fragB_row_f32(wg1, 64, cb * 16, ks * 32, lane);
                dacc[cb] = __builtin_amdgcn_mfma_f32_16x16x32_bf16(a, bb, dacc[cb], 0, 0, 0);
            }
        }
#pragma unroll
        for (int cb = 0; cb < 4; ++cb)
#pragma unroll
            for (int r = 0; r < 4; ++r)
                bufT[(wv * 16 + lg * 4 + r) * 65 + cb * 16 + c16] = dacc[cb][r];
    }
    __syncthreads();
    // ---- X = relu(A @ T1) -> h0x ----
    {
        f32x4 dacc[4] = {};
#pragma unroll
        for (int ks = 0; ks < 2; ++ks) {
            const bf16x8 a = fragA_f32(bufA, 65, wv * 16, ks * 32, lane);
#pragma unroll
            for (int cb = 0; cb < 4; ++cb) {
                const bf16x8 bb = fragB_col_f32(bufT, 65, cb * 16, ks * 32, lane);
                dacc[cb] = __builtin_amdgcn_mfma_f32_16x16x32_bf16(a, bb, dacc[cb], 0, 0, 0);
            }
        }
        __syncthreads();
#pragma unroll
        for (int cb = 0; cb < 4; ++cb)
#pragma unroll
            for (int r = 0; r < 4; ++r)
                h0x[(wv * 16 + lg * 4 + r) * 65 + cb * 16 + c16] = fmaxf(dacc[cb][r], 0.f);
    }
    __syncthreads();
    // ---- T2 = X @ wg2^T -> bufT ----
    {
        f32x4 dacc[4] = {};
#pragma unroll
        for (int ks = 0; ks < 2; ++ks) {
            const bf16x8 a = fragA_f32(h0x, 65, wv * 16, ks * 32, lane);
#pragma unroll
            for (int cb = 0; cb < 4; ++cb) {
                const bf16x8 bb = fragB_row_f32(wg2, 64, cb * 16, ks * 32, lane);
                dacc[cb] = __builtin_amdgcn_mfma_f32_16x16x32_bf16(a, bb, dacc[cb], 0, 0, 0);
            }
        }
        __syncthreads();
#pragma unroll
        for (int cb = 0; cb < 4; ++cb)
#pragma unroll
            for (int r = 0; r < 4; ++r)
                bufT[(wv * 16 + lg * 4 + r) * 65 + cb * 16 + c16] = dacc[cb][r];
    }
    __syncthreads();
    // ---- Hg = relu(A @ T2) -> h0x ----
    {
        f32x4 dacc[4] = {};
#pragma unroll
        for (int ks = 0; ks < 2; ++ks) {
            const bf16x8 a = fragA_f32(bufA, 65, wv * 16, ks * 32, lane);
#pragma unroll
            for (int cb = 0; cb < 4; ++cb) {
                const bf16x8 bb = fragB_col_f32(bufT, 65, cb * 16, ks * 32, lane);
                dacc[cb] = __builtin_amdgcn_mfma_f32_16x16x32_bf16(a, bb, dacc[cb], 0, 0, 0);
            }
        }
        __syncthreads();
#pragma unroll
        for (int cb = 0; cb < 4; ++cb)
#pragma unroll
            for (int r = 0; r < 4; ++r)
                h0x[(wv * 16 + lg * 4 + r) * 65 + cb * 16 + c16] = fmaxf(dacc[cb][r], 0.f);
    }
    __syncthreads();
    // ---- HgPk: fragment-packed bf16 (B-operand: cols m, k = d) ----
    for (int e = t; e < 4096; e += 256) {
        const int j = e & 7, l = (e >> 3) & 63, ks = (e >> 9) & 1, mb = e >> 10;
        const int m = mb * 16 + (l & 15);
        const int g = l >> 4;
        const int km = (j < 4) ? g * 4 + j : 16 + g * 4 + (j - 4);
        HgPk[(size_t)b * 4096 + e] = f2bf(h0x[m * 65 + ks * 32 + km]);
    }
    // ---- G = Hg @ wn2t^T, per-64-col chunk -> bufT -> Gpk (fused k_gmat) ----
    for (int cc = 0; cc < 4; ++cc) {
        __syncthreads();
        f32x4 dacc[4] = {};
#pragma unroll
        for (int ks = 0; ks < 2; ++ks) {
            const bf16x8 a = fragA_f32(h0x, 65, wv * 16, ks * 32, lane);
#pragma unroll
            for (int cb = 0; cb < 4; ++cb) {
                const bf16x8 bb = fragB_row_f32(wn2t, 64, cc * 64 + cb * 16, ks * 32, lane);
                dacc[cb] = __builtin_amdgcn_mfma_f32_16x16x32_bf16(a, bb, dacc[cb], 0, 0, 0);
            }
        }
#pragma unroll
        for (int cb = 0; cb < 4; ++cb)
#pragma unroll
            for (int r = 0; r < 4; ++r)
                bufT[(wv * 16 + lg * 4 + r) * 65 + cb * 16 + c16] = dacc[cb][r];
        __syncthreads();
        // pack chunk: G[m][c], c = cc*64 + cl
        for (int e = t; e < 4096; e += 256) {
            const int m = e >> 6, cl = e & 63;
            const int c = cc * 64 + cl;
            const int cbg = c >> 4, cc16 = c & 15;
            const int ks = m >> 5, km = m & 31;
            const int g = (km & 15) >> 2;
            const int j = (km & 3) + ((km >= 16) ? 4 : 0);
            Gpk[(size_t)b * 16384 + ((cbg * 2 + ks) * 64 + g * 16 + cc16) * 8 + j] =
                f2bf(bufT[m * 65 + cl]);
        }
    }
}

// ---------------------------------------------------------------------------
// Kernel C (MFMA): logits -> softmax -> out = fmap + attn @ G. (R6 form)
// ---------------------------------------------------------------------------
__global__ __launch_bounds__(256) void k_inject(
    const float* __restrict__ fmap, const unsigned short* __restrict__ projPk,
    const unsigned short* __restrict__ HgPk, const unsigned short* __restrict__ Gpk,
    float* __restrict__ out)
{
    __shared__ unsigned short attnL[64 * 72];

    const int b = blockIdx.y;
    const int tile = blockIdx.x;
    const int p0 = tile * 64;
    const int t = threadIdx.x;
    const int nb = t >> 6, l = t & 63;
    const int g = l >> 4, c16 = l & 15;

    const bf16x8* pp = (const bf16x8*)(projPk + (size_t)b * PPB);
    bf16x8 atok[2];
    atok[0] = pp[((tile * 4 + nb) * 2 + 0) * 64 + l];
    atok[1] = pp[((tile * 4 + nb) * 2 + 1) * 64 + l];

    const bf16x8* hp = (const bf16x8*)(HgPk + (size_t)b * 4096);
    f32x4 accL[4] = {};
#pragma unroll
    for (int ks = 0; ks < 2; ++ks)
#pragma unroll
        for (int mb = 0; mb < 4; ++mb)
            accL[mb] = __builtin_amdgcn_mfma_f32_16x16x32_bf16(atok[ks], hp[(mb * 2 + ks) * 64 + l], accL[mb], 0, 0, 0);

#pragma unroll
    for (int mb = 0; mb < 4; ++mb)
#pragma unroll
        for (int r = 0; r < 4; ++r) accL[mb][r] *= 0.125f;

    float mx[4], sm[4], inv[4];
#pragma unroll
    for (int r = 0; r < 4; ++r)
        mx[r] = fmaxf(fmaxf(accL[0][r], accL[1][r]), fmaxf(accL[2][r], accL[3][r]));
#pragma unroll
    for (int st = 1; st < 16; st <<= 1)
#pragma unroll
        for (int r = 0; r < 4; ++r) mx[r] = fmaxf(mx[r], __shfl_xor(mx[r], st, 64));
#pragma unroll
    for (int r = 0; r < 4; ++r) sm[r] = 0.f;
#pragma unroll
    for (int mb = 0; mb < 4; ++mb)
#pragma unroll
        for (int r = 0; r < 4; ++r) {
            const float e = __expf(accL[mb][r] - mx[r]);
            accL[mb][r] = e; sm[r] += e;
        }
#pragma unroll
    for (int st = 1; st < 16; st <<= 1)
#pragma unroll
        for (int r = 0; r < 4; ++r) sm[r] += __shfl_xor(sm[r], st, 64);
#pragma unroll
    for (int r = 0; r < 4; ++r) inv[r] = 1.f / sm[r];

#pragma unroll
    for (int mb = 0; mb < 4; ++mb)
#pragma unroll
        for (int r = 0; r < 4; ++r)
            attnL[(nb * 16 + g * 4 + r) * 72 + mb * 16 + c16] = f2bf(accL[mb][r] * inv[r]);
    __syncthreads();

    const int nrow = nb * 16 + c16;
    bf16x8 battn[2];
#pragma unroll
    for (int ks = 0; ks < 2; ++ks) {
        const ushort4 lo = *(const ushort4*)&attnL[nrow * 72 + ks * 32 + g * 4];
        const ushort4 hi = *(const ushort4*)&attnL[nrow * 72 + ks * 32 + 16 + g * 4];
        bf16x8 f;
        f[0] = (short)lo.x; f[1] = (short)lo.y; f[2] = (short)lo.z; f[3] = (short)lo.w;
        f[4] = (short)hi.x; f[5] = (short)hi.y; f[6] = (short)hi.z; f[7] = (short)hi.w;
        battn[ks] = f;
    }

    const bf16x8* gp = (const bf16x8*)(Gpk + (size_t)b * 16384);
    const float* fb = fmap + (size_t)b * CC * HWP;
    float* ob = out + (size_t)b * CC * HWP;
    const int ncol = p0 + nb * 16 + g * 4;

#pragma unroll
    for (int cb = 0; cb < 16; ++cb) {
        f32x4 acc = {};
#pragma unroll
        for (int ks = 0; ks < 2; ++ks)
            acc = __builtin_amdgcn_mfma_f32_16x16x32_bf16(battn[ks], gp[(cb * 2 + ks) * 64 + l], acc, 0, 0, 0);
        const size_t off = (size_t)(cb * 16 + c16) * HWP + ncol;
        const float4 f4 = *(const float4*)&fb[off];
        float4 o4;
        o4.x = f4.x + acc[0];
        o4.y = f4.y + acc[1];
        o4.z = f4.z + acc[2];
        o4.w = f4.w + acc[3];
        *(float4*)&ob[off] = o4;
    }
}

// ---------------------------------------------------------------------------
extern "C" void kernel_launch(void* const* d_in, const int* in_sizes, int n_in,
                              void* d_out, int out_size, void* d_ws, size_t ws_size,
                              hipStream_t stream)
{
    const float* fmap = (const float*)d_in[0];
    const float* ws1  = (const float*)d_in[1];
    const float* bs1  = (const float*)d_in[2];
    const float* ws2  = (const float*)d_in[3];
    const float* bs2  = (const float*)d_in[4];
    const float* wt2n = (const float*)d_in[5];
    const float* wn2t = (const float*)d_in[6];
    const float* wg1  = (const float*)d_in[7];
    const float* wg2  = (const float*)d_in[8];
    float* out = (float*)d_out;

    char* ws = (char*)d_ws;
    float*          scores = (float*)(ws + WS_SCORES_B);
    unsigned short* projPk = (unsigned short*)(ws + WS_PROJ_B);
    unsigned short* HgPk   = (unsigned short*)(ws + WS_HGPK_B);
    unsigned short* Gpk    = (unsigned short*)(ws + WS_GPK_B);
    unsigned short* wpk    = (unsigned short*)(ws + WS_WPK_B);

    const dim3 blk(256);
    k_prep<<<dim3(128), blk, 0, stream>>>(ws1, wt2n, wpk);
    k_mfma_a<<<dim3(HWP / 64, BB), blk, 0, stream>>>(fmap, wpk, bs1, ws2, bs2, scores, projPk);
    k_graph<<<dim3(BB), blk, 0, stream>>>(scores, projPk, wg1, wg2, wn2t, HgPk, Gpk);
    k_inject<<<dim3(HWP / 64, BB), blk, 0, stream>>>(fmap, projPk, HgPk, Gpk, out);
}